// Round 4
// baseline (523.013 us; speedup 1.0000x reference)
//
#include <hip/hip_runtime.h>
#include <hip/hip_bf16.h>

// Problem constants: B=8, N=2048, D=384, R=64, H=W=256.
// Inputs:  x (B,N,D) f32, segments (B,H,W) i32, prototypes (1,R,D) f32.
// Outputs (FLOAT32, concat): out (B,N,D) | segments (B,H,W) | loss (1) | C (B,N,R)
//   (mixed-dtype reference tuple -> harness uses float* for d_out; proven by
//    byte-identical 2048.656 absmax across rounds 2/3: my bf16 outSeg chunk
//    read as f32 0x45000000 == 2048.0 inside the harness's Output-0 region.)
//
// Memory plan:
//  * prox bitmask (2048 bits/node) lives INSIDE the out chunk: node n's mask
//    occupies the first 64 u32 of its own 1536-byte output row (f32==u32 size).
//    k_pool reads its own row's mask before overwriting it; no cross-row writes.
//  * rawS -> s -> C computed IN PLACE (f32) in the outC chunk.
//  * cinv (1/||C_n||) borrows the outSeg chunk; k_segout runs last.
//  * d_ws use: kn + xinv + mask + colsum + lossacc = 231,432 bytes only.
#define NB 8
#define NN 2048
#define ND 384
#define NR 64
#define OUT_ELEMS (NB*NN*ND)        // 6291456
#define SEG_ELEMS (NB*256*256)      // 524288

__device__ inline float wsum(float v){
  #pragma unroll
  for(int o=32;o;o>>=1) v += __shfl_xor(v,o,64);
  return v;
}
__device__ inline float wmax(float v){
  #pragma unroll
  for(int o=32;o;o>>=1) v = fmaxf(v,__shfl_xor(v,o,64));
  return v;
}

// ---- normalize prototypes -> kn (f32, unit rows) ----
__global__ void k_proto(const float* __restrict__ protos, float* __restrict__ kn){
  int r = blockIdx.x, l = threadIdx.x;
  float v[6]; float ss = 0.f;
  #pragma unroll
  for(int i=0;i<6;i++){ v[i] = protos[r*ND + l*6 + i]; ss += v[i]*v[i]; }
  ss = wsum(ss);
  float inv = 1.f / fmaxf(sqrtf(ss), 1e-8f);
  #pragma unroll
  for(int i=0;i<6;i++) kn[r*ND + l*6 + i] = v[i]*inv;
}

// ---- per-node 1/max(||x||, eps) ----
__global__ void k_xinv(const float* __restrict__ x, float* __restrict__ xinv){
  int node = blockIdx.x*4 + (threadIdx.x>>6);
  int l = threadIdx.x & 63;
  const float* xr = x + node*ND;
  float ss = 0.f;
  #pragma unroll
  for(int p=0;p<6;p++){ float a = xr[l + 64*p]; ss += a*a; }
  ss = wsum(ss);
  if(l==0) xinv[node] = 1.f / fmaxf(sqrtf(ss), 1e-8f);
}

// ---- segments -> node mask (ws) + prox bits (into out-chunk rows) ----
__global__ void k_seg(const int* __restrict__ seg, float* __restrict__ mask, unsigned* proxv){
  int idx = blockIdx.x*256 + threadIdx.x;         // < B*H*W = 524288
  int b = idx >> 16, p = idx & 65535, i = p >> 8, j = p & 255;
  int s = seg[idx];
  int base = b << 11;                              // b*N
  mask[base + s] = 1.f;                            // benign race: same value
  if(j < 255){
    int s2 = seg[idx+1];
    if(s != s2 && s != 0 && s2 != 0){
      atomicOr(&proxv[(base+s)*ND  + (s2>>5)], 1u<<(s2&31));
      atomicOr(&proxv[(base+s2)*ND + (s >>5)], 1u<<(s &31));
    }
  }
  if(i < 255){
    int s2 = seg[idx+256];
    if(s != s2 && s != 0 && s2 != 0){
      atomicOr(&proxv[(base+s)*ND  + (s2>>5)], 1u<<(s2&31));
      atomicOr(&proxv[(base+s2)*ND + (s >>5)], 1u<<(s &31));
    }
  }
}

// ---- Csim GEMM: rawS[node][r] = (dot(x_node, kn_r)*xinv + 1)/2 -> outC f32 ----
__global__ __launch_bounds__(256) void k_csim(const float* __restrict__ x,
                                              const float* __restrict__ kn,
                                              const float* __restrict__ xinv,
                                              float* __restrict__ Sout){
  __shared__ float xT[32*68];
  __shared__ float kT[32*68];
  int t = threadIdx.x;
  int m0 = blockIdx.x * 64;
  float acc[4][4] = {};
  int mload = t>>2, koff = (t&3)*8;
  int mb = (t>>4)*4, rb = (t&15)*4;
  for(int c=0;c<12;c++){
    int k0 = c*32;
    __syncthreads();
    const float4* xg = (const float4*)(x + (m0+mload)*ND + k0 + koff);
    float4 a = xg[0], bq = xg[1];
    xT[(koff+0)*68+mload]=a.x;  xT[(koff+1)*68+mload]=a.y;  xT[(koff+2)*68+mload]=a.z;  xT[(koff+3)*68+mload]=a.w;
    xT[(koff+4)*68+mload]=bq.x; xT[(koff+5)*68+mload]=bq.y; xT[(koff+6)*68+mload]=bq.z; xT[(koff+7)*68+mload]=bq.w;
    const float4* kg = (const float4*)(kn + mload*ND + k0 + koff);
    float4 ka = kg[0], kb = kg[1];
    kT[(koff+0)*68+mload]=ka.x; kT[(koff+1)*68+mload]=ka.y; kT[(koff+2)*68+mload]=ka.z; kT[(koff+3)*68+mload]=ka.w;
    kT[(koff+4)*68+mload]=kb.x; kT[(koff+5)*68+mload]=kb.y; kT[(koff+6)*68+mload]=kb.z; kT[(koff+7)*68+mload]=kb.w;
    __syncthreads();
    for(int k=0;k<32;k++){
      float xv[4], kv[4];
      *(float4*)xv = *(const float4*)&xT[k*68+mb];
      *(float4*)kv = *(const float4*)&kT[k*68+rb];
      #pragma unroll
      for(int mi=0;mi<4;mi++)
        #pragma unroll
        for(int ri=0;ri<4;ri++) acc[mi][ri] += xv[mi]*kv[ri];
    }
  }
  #pragma unroll
  for(int mi=0;mi<4;mi++){
    float xin = xinv[m0+mb+mi];
    #pragma unroll
    for(int ri=0;ri<4;ri++)
      Sout[(m0+mb+mi)*NR + rb + ri] = (acc[mi][ri]*xin + 1.f)*0.5f;
  }
}

// ---- rawS -> normalized s, in place (f32) ----
__global__ void k_rowops(float* Smat){
  int node = blockIdx.x*4 + (threadIdx.x>>6);
  int l = threadIdx.x & 63;
  float raw = Smat[node*NR + l];
  float ssum = wsum(raw);
  Smat[node*NR + l] = raw / ssum;
}

// ---- colsum[b][r] = sum_n s[b,n,r] ----
__global__ void k_colsum(const float* __restrict__ Smat, float* __restrict__ colsum){
  __shared__ float sh[256];
  int b = blockIdx.x >> 3, chunk = blockIdx.x & 7;
  int r = threadIdx.x & 63, nsub = threadIdx.x >> 6;
  float acc = 0.f;
  int nbase = b*NN + chunk*256 + nsub*64;
  for(int i=0;i<64;i++) acc += Smat[(nbase+i)*NR + r];
  sh[threadIdx.x] = acc;
  __syncthreads();
  if(threadIdx.x < 64)
    atomicAdd(&colsum[b*NR + threadIdx.x],
              sh[threadIdx.x]+sh[threadIdx.x+64]+sh[threadIdx.x+128]+sh[threadIdx.x+192]);
}

// ---- DEC KL loss partials ----
__global__ void k_loss(const float* __restrict__ Smat, const float* __restrict__ colsum,
                       const float* __restrict__ mask, float* __restrict__ lossacc){
  __shared__ float shk[4], shm[4];
  int w = threadIdx.x>>6, l = threadIdx.x&63;
  int node = blockIdx.x*4 + w;
  int b = node >> 11;
  float s = Smat[node*NR + l];
  float csm = colsum[(b<<6) + l];
  float p = s*s/(csm + 1e-8f);
  float ps = wsum(p);
  float P = p/(ps + 1e-8f);
  float term = P*(logf(P + 1e-8f) - logf(s + 1e-8f));
  float kl = wsum(term);
  if(l==0){ float mv = mask[node]; shk[w] = kl*mv; shm[w] = mv; }
  __syncthreads();
  if(threadIdx.x==0){
    atomicAdd(&lossacc[0], shk[0]+shk[1]+shk[2]+shk[3]);
    atomicAdd(&lossacc[1], shm[0]+shm[1]+shm[2]+shm[3]);
  }
}

__global__ void k_fin(const float* __restrict__ lossacc, float* __restrict__ outLoss){
  if(threadIdx.x==0) outLoss[0] = lossacc[0]/(lossacc[1]+1e-8f);
}

// ---- s -> C = softmax(s) in place (f32) + cinv = 1/||C|| ----
__global__ void k_fc(float* Smat, float* __restrict__ cinv){
  int node = blockIdx.x*4 + (threadIdx.x>>6);
  int l = threadIdx.x & 63;
  float s = Smat[node*NR + l];
  float mx = wmax(s);
  float e = expf(s - mx);
  float Z = wsum(e);
  float c = e / Z;
  float cn = sqrtf(wsum(c*c));
  Smat[node*NR + l] = c;
  if(l==0) cinv[node] = 1.f/cn;
}

__global__ void k_segout(const int* __restrict__ seg, float* __restrict__ o){
  int i = blockIdx.x*256 + threadIdx.x;
  o[i] = (float)seg[i];
}

// ---- sparse fused pooling: one wave per output row ----
// outb doubles as the prox-bit store (first 64 u32 of each 384-f32 row).
// Per-node factor cinv_n cancels in row normalization; only cinv_m applied.
__global__ __launch_bounds__(256) void k_pool(const float* __restrict__ x,
                                              float* outb,
                                              const float* __restrict__ Cmat,
                                              const float* __restrict__ cinv){
  int w = threadIdx.x>>6, l = threadIdx.x&63;
  int b = blockIdx.x & 7, nb = blockIdx.x >> 3;   // batch-major for L2/XCD locality
  int n = nb*4 + w;
  int node = (b<<11) + n;
  const unsigned* proxv = (const unsigned*)outb;
  unsigned wordL = proxv[node*ND + l];            // own row's 2048-bit mask
  if(l == (n>>5)) wordL |= 1u << (n&31);          // diagonal always present
  float cn = Cmat[node*NR + l];
  const float* xb = x + (b<<11)*ND;
  const float* Cb = Cmat + (b<<11)*NR;
  const float* civ = cinv + (b<<11);
  float a0=0,a1=0,a2=0,a3=0,a4=0,a5=0, rs=0;
  for(int wi=0; wi<64; wi++){
    unsigned word = __shfl((int)wordL, wi, 64);
    int mbase = wi<<5;
    while(word){
      int j = __builtin_ctz(word); word &= word-1;
      int m = mbase + j;
      float cm = Cb[m*NR + l];
      float wv = wsum(cn*cm) * civ[m];
      rs += wv;
      const float* xr = xb + m*ND;
      a0 += wv*xr[l];
      a1 += wv*xr[l+64];
      a2 += wv*xr[l+128];
      a3 += wv*xr[l+192];
      a4 += wv*xr[l+256];
      a5 += wv*xr[l+320];
    }
  }
  float inv = 1.f/(rs + 1e-8f);
  float* orow = outb + node*ND;
  orow[l]     = a0*inv;
  orow[l+64]  = a1*inv;
  orow[l+128] = a2*inv;
  orow[l+192] = a3*inv;
  orow[l+256] = a4*inv;
  orow[l+320] = a5*inv;
}

extern "C" void kernel_launch(void* const* d_in, const int* in_sizes, int n_in,
                              void* d_out, int out_size, void* d_ws, size_t ws_size,
                              hipStream_t stream) {
  const float* x      = (const float*)d_in[0];     // (B,N,D) f32
  const int*   seg    = (const int*)d_in[1];       // (B,H,W) i32
  const float* protos = (const float*)d_in[2];     // (1,R,D) f32

  float* out     = (float*)d_out;                  // (B,N,D)
  float* outSeg  = out + OUT_ELEMS;                // (B,H,W)
  float* outLoss = outSeg + SEG_ELEMS;             // scalar
  float* outC    = outLoss + 1;                    // (B,N,R)

  unsigned* proxv = (unsigned*)d_out;              // prox rows inside out chunk
  float*    cinv  = outSeg;                        // 16384 f32, overwritten by k_segout last

  float* ws      = (float*)d_ws;                   // total use: 231,432 bytes
  float* kn      = ws;                             // 24576 f32
  float* xinv    = kn + NR*ND;                     // 16384
  float* maskp   = xinv + NB*NN;                   // 16384
  float* colsum  = maskp + NB*NN;                  // 512
  float* lossacc = colsum + NB*NR;                 // 2

  hipMemsetAsync(out, 0, (size_t)OUT_ELEMS*4, stream);                    // zero prox region
  hipMemsetAsync(maskp, 0, (size_t)(NB*NN + NB*NR + 2)*4, stream);        // mask+colsum+lossacc

  k_proto <<<dim3(NR),           dim3(64),  0, stream>>>(protos, kn);
  k_xinv  <<<dim3(NB*NN/4),      dim3(256), 0, stream>>>(x, xinv);
  k_seg   <<<dim3(NB*65536/256), dim3(256), 0, stream>>>(seg, maskp, proxv);
  k_csim  <<<dim3(NB*NN/64),     dim3(256), 0, stream>>>(x, kn, xinv, outC);
  k_rowops<<<dim3(NB*NN/4),      dim3(256), 0, stream>>>(outC);
  k_colsum<<<dim3(NB*8),         dim3(256), 0, stream>>>(outC, colsum);
  k_loss  <<<dim3(NB*NN/4),      dim3(256), 0, stream>>>(outC, colsum, maskp, lossacc);
  k_fin   <<<dim3(1),            dim3(64),  0, stream>>>(lossacc, outLoss);
  k_fc    <<<dim3(NB*NN/4),      dim3(256), 0, stream>>>(outC, cinv);
  k_pool  <<<dim3(NB*NN/4),      dim3(256), 0, stream>>>(x, out, outC, cinv);
  k_segout<<<dim3(SEG_ELEMS/256),dim3(256), 0, stream>>>(seg, outSeg);
}